// Round 11
// baseline (1338.544 us; speedup 1.0000x reference)
//
#include <hip/hip_runtime.h>
#include <hip/hip_bf16.h>

// ---- problem constants ----
#define E_NUM 16
#define TOPK 4
#define H_DIM 2048
#define I_DIM 1408
#define IS_DIM 5632
#define M_TOK 4096

typedef __attribute__((ext_vector_type(8))) short short8;
typedef __attribute__((ext_vector_type(4))) float f32x4;
typedef __attribute__((ext_vector_type(16))) float f32x16;

static __device__ __forceinline__ unsigned short f2bf(float f) {
    unsigned int u = __float_as_uint(f);
    unsigned int r = (u + 0x7FFFu + ((u >> 16) & 1u)) >> 16;
    return (unsigned short)r;
}

static __device__ __forceinline__ void gl16(const unsigned short* g, unsigned short* l) {
    __builtin_amdgcn_global_load_lds(
        (const __attribute__((address_space(1))) unsigned int*)g,
        (__attribute__((address_space(3))) unsigned int*)l, 16, 0, 0);
}

// ---------------- router: fp32 logits, softmax, top-4, shared gate ----------------
__global__ __launch_bounds__(256) void k_router(
    const float* __restrict__ x, const float* __restrict__ gw,
    const float* __restrict__ sgw, int* __restrict__ counts,
    int* __restrict__ ltok, float* __restrict__ lcoef, float* __restrict__ sg)
{
    const int wid = threadIdx.x >> 6, lane = threadIdx.x & 63;
    const int t = blockIdx.x * 4 + wid;
    const float* xr = x + (size_t)t * H_DIM;
    float xv[32];
#pragma unroll
    for (int i = 0; i < 32; ++i) xv[i] = xr[i * 64 + lane];

    float lg[E_NUM];
    for (int e = 0; e < E_NUM; ++e) {
        const float* g = gw + (size_t)e * H_DIM;
        float s = 0.f;
#pragma unroll
        for (int i = 0; i < 32; ++i) s += xv[i] * g[i * 64 + lane];
#pragma unroll
        for (int off = 32; off; off >>= 1) s += __shfl_xor(s, off);
        lg[e] = s;
    }
    {
        float s = 0.f;
#pragma unroll
        for (int i = 0; i < 32; ++i) s += xv[i] * sgw[i * 64 + lane];
#pragma unroll
        for (int off = 32; off; off >>= 1) s += __shfl_xor(s, off);
        if (lane == 0) sg[t] = 1.f / (1.f + __expf(-s));
    }
    float mx = lg[0];
#pragma unroll
    for (int e = 1; e < E_NUM; ++e) mx = fmaxf(mx, lg[e]);
    float sum = 0.f, w[E_NUM];
#pragma unroll
    for (int e = 0; e < E_NUM; ++e) { w[e] = __expf(lg[e] - mx); sum += w[e]; }
    float inv = 1.f / sum;
#pragma unroll
    for (int e = 0; e < E_NUM; ++e) w[e] *= inv;

    if (lane == 0) {
        for (int j = 0; j < TOPK; ++j) {
            float best = -1.f; int bi = 0;
            for (int e = 0; e < E_NUM; ++e) if (w[e] > best) { best = w[e]; bi = e; }
            int pos = atomicAdd(&counts[bi], 1);
            ltok[bi * M_TOK + pos]  = t;
            lcoef[bi * M_TOK + pos] = best;
            w[bi] = -2.f;
        }
    }
}

__global__ void k_prefix(const int* __restrict__ counts, int* __restrict__ base) {
    if (threadIdx.x == 0) {
        int a = 0;
        for (int e = 0; e < E_NUM; ++e) { base[e] = a; a += counts[e]; }
        base[E_NUM] = a;
    }
}

// ---------------- fp32 -> bf16 conversion (grid-stride) ----------------
__global__ __launch_bounds__(256) void k_cvtw(const float* __restrict__ src,
                                              unsigned short* __restrict__ dst, size_t n8)
{
    size_t stride = (size_t)gridDim.x * 256;
    for (size_t t = (size_t)blockIdx.x * 256 + threadIdx.x; t < n8; t += stride) {
        size_t i = t * 8;
        float4 a = *(const float4*)(src + i);
        float4 b = *(const float4*)(src + i + 4);
        union { unsigned short u[8]; short8 v; } o;
        o.u[0] = f2bf(a.x); o.u[1] = f2bf(a.y); o.u[2] = f2bf(a.z); o.u[3] = f2bf(a.w);
        o.u[4] = f2bf(b.x); o.u[5] = f2bf(b.y); o.u[6] = f2bf(b.z); o.u[7] = f2bf(b.w);
        *(short8*)(dst + i) = o.v;
    }
}

// fp32 -> bf16 with gate/up 32-row-chunk interleave within TWOI-row groups.
// dst row pr: chunk q=pr>>5 even -> gate row (q>>1)*32+(pr&31); odd -> +NOFF.
template<int TWOI, int NOFF>
__global__ __launch_bounds__(256) void k_cvtp(const float* __restrict__ src,
                                              unsigned short* __restrict__ dst, size_t n8)
{
    size_t stride = (size_t)gridDim.x * 256;
    for (size_t t = (size_t)blockIdx.x * 256 + threadIdx.x; t < n8; t += stride) {
        size_t i = t * 8;
        unsigned drow = (unsigned)(i >> 11);
        unsigned col  = (unsigned)(i & 2047u);
        unsigned grp = drow / (unsigned)TWOI;
        unsigned rr  = drow - grp * (unsigned)TWOI;
        unsigned q = rr >> 5, rm = rr & 31u;
        unsigned srow = ((q >> 1) << 5) + rm + ((q & 1u) ? (unsigned)NOFF : 0u);
        const float* s = src + (((size_t)grp * TWOI + srow) << 11) + col;
        float4 a = *(const float4*)s;
        float4 b = *(const float4*)(s + 4);
        union { unsigned short u[8]; short8 v; } o;
        o.u[0] = f2bf(a.x); o.u[1] = f2bf(a.y); o.u[2] = f2bf(a.z); o.u[3] = f2bf(a.w);
        o.u[4] = f2bf(b.x); o.u[5] = f2bf(b.y); o.u[6] = f2bf(b.z); o.u[7] = f2bf(b.w);
        *(short8*)(dst + i) = o.v;
    }
}

// ---------------- 256x128 3-deep-pipelined 32x32x16 MFMA GEMM ----------------
// BM=256, BN=128, BK=64. 512 threads = 8 waves (4M x 2N), per-wave 64x64 =
// 2x2 fragments of 32x32. Three LDS buffers (144 KiB), tile t reads buf[t%3],
// stages t+2 into buf[(t+2)%3]; one barrier + one counted vmcnt(6) per K-tile.
// A/B frag: lane l -> row/col l&31, k = (l>>5)*8 + e. C/D: col=lane&31,
// row = (reg&3) + 8*(reg>>2) + 4*(lane>>5)  [HW-verified m74/m101].
template<int MODE, int KDIM, long long BSTR, int KSPLIT>
__global__ __launch_bounds__(512, 2) void k_gemm(
    const unsigned short* __restrict__ Abase,
    const unsigned short* __restrict__ Bbase,
    void* __restrict__ outp,
    const int* __restrict__ ltok, const float* __restrict__ lcoef,
    const int* __restrict__ counts, const int* __restrict__ basearr,
    const float* __restrict__ sg)
{
    constexpr bool UP = (MODE == 0 || MODE == 2);
    constexpr int OSTR = (MODE == 0) ? IS_DIM : I_DIM;   // h row stride (UP only)
    constexpr int KCH = KDIM / KSPLIT;
    constexpr int NT = KCH / 64;

    extern __shared__ unsigned short smem[];
    unsigned short* sA = smem;            // [3 buf][256 rows][64]
    unsigned short* sB = smem + 49152;    // [3 buf][128 rows][64]

    const int tid = threadIdx.x;
    const int lane = tid & 63, wid = tid >> 6;
    const int wr = wid >> 1, wc = wid & 1;       // 4M x 2N wave grid
    const int l31 = lane & 31, lh = lane >> 5;

    // ---- bijective XCD-chunk swizzle over (x,y), y-major within chunk ----
    const unsigned gx = gridDim.x, gy = gridDim.y;
    const unsigned nwg = gx * gy;
    const unsigned orig = blockIdx.y * gx + blockIdx.x;
    const unsigned q8 = nwg >> 3, r8 = nwg & 7;
    const unsigned xcd = orig & 7, off8 = orig >> 3;
    const unsigned wg = ((xcd < r8) ? xcd * (q8 + 1) : r8 * (q8 + 1) + (xcd - r8) * q8) + off8;
    const int n0 = (int)(wg / gy) * 128;
    const int r0 = (int)(wg % gy) * 256;
    const int e  = blockIdx.z;

    int cnt = M_TOK, gbase = 0;
    if constexpr (MODE == 2 || MODE == 3) {
        cnt = counts[e];
        if (r0 >= cnt) return;
        gbase = basearr[e];
    }
    const int kbeg = (KSPLIT > 1) ? e * KCH : 0;
    const unsigned short* Bexp = Bbase + (size_t)e * (size_t)BSTR;

    // ---- staging source pointers (pre-swizzled, fixed across K) ----
    const unsigned short* aptr[2][2];
#pragma unroll
    for (int h = 0; h < 2; ++h) {
#pragma unroll
        for (int i = 0; i < 2; ++i) {
            const int eo = (i * 512 + tid) * 8;        // elem offset in 128-row half
            const int prow = eo >> 6;                  // 0..127
            const int kch = ((eo >> 3) & 7) ^ (prow & 7);
            const int lrow = h * 128 + prow;
            int ar;
            if constexpr (MODE == 0 || MODE == 1) ar = r0 + lrow;
            else {
                int rr2 = r0 + lrow; if (rr2 > cnt - 1) rr2 = cnt - 1;
                ar = (MODE == 2) ? ltok[e * M_TOK + rr2] : (gbase + rr2);
            }
            aptr[h][i] = Abase + (size_t)ar * KDIM + kbeg + kch * 8;
        }
    }
    const unsigned short* bptr[2];
#pragma unroll
    for (int i = 0; i < 2; ++i) {
        const int eo = (i * 512 + tid) * 8;
        const int prow = eo >> 6;                      // 0..127
        const int kch = ((eo >> 3) & 7) ^ (prow & 7);
        bptr[i] = Bexp + (size_t)(n0 + prow) * KDIM + kbeg + kch * 8;
    }

    f32x16 acc[2][2];
#pragma unroll
    for (int m = 0; m < 2; ++m)
#pragma unroll
        for (int n = 0; n < 2; ++n)
#pragma unroll
            for (int r = 0; r < 16; ++r) acc[m][n][r] = 0.f;

    auto STAGE = [&](int buf, int kt) {
#pragma unroll
        for (int i = 0; i < 2; ++i)
            gl16(aptr[0][i] + kt, &sA[buf * 16384 + (i * 512 + tid) * 8]);
#pragma unroll
        for (int i = 0; i < 2; ++i)
            gl16(aptr[1][i] + kt, &sA[buf * 16384 + 8192 + (i * 512 + tid) * 8]);
#pragma unroll
        for (int i = 0; i < 2; ++i)
            gl16(bptr[i] + kt, &sB[buf * 8192 + (i * 512 + tid) * 8]);
    };

    // prologue: tiles 0 and 1 (12 loads); wait until tile 0's 6 done
    STAGE(0, 0);
    STAGE(1, 64);
    asm volatile("s_waitcnt vmcnt(6)" ::: "memory");
    __builtin_amdgcn_s_barrier();

    short8 af[8], bf[8];
    int rb = 0;

#pragma unroll 1
    for (int t = 0; t < NT; ++t) {
        const bool pf = (t + 2 < NT);
        int wb = rb + 2; if (wb >= 3) wb -= 3;
        const int cbA = rb * 16384, cbB = rb * 8192;

        // ---- issue stage of tile t+2 FIRST (T3 ordering) ----
        if (pf) STAGE(wb, (t + 2) * 64);

        // ---- LDS -> registers (16 x ds_read_b128) ----
        // frag read: row = base + l31; k-granule c8 = s*2 + lh (s = k16-step)
#pragma unroll
        for (int mi = 0; mi < 2; ++mi) {
            const int row = wr * 64 + mi * 32 + l31;
#pragma unroll
            for (int s = 0; s < 4; ++s) {
                const int c8 = (s << 1) + lh;
                af[mi * 4 + s] = *(const short8*)&sA[cbA + (row << 6) + ((c8 ^ (row & 7)) << 3)];
            }
        }
#pragma unroll
        for (int nf = 0; nf < 2; ++nf) {
            const int row = wc * 64 + nf * 32 + l31;
#pragma unroll
            for (int s = 0; s < 4; ++s) {
                const int c8 = (s << 1) + lh;
                bf[nf * 4 + s] = *(const short8*)&sB[cbB + (row << 6) + ((c8 ^ (row & 7)) << 3)];
            }
        }

        // ---- 16 x mfma_f32_32x32x16_bf16 ----
        __builtin_amdgcn_s_setprio(1);
#pragma unroll
        for (int s = 0; s < 4; ++s)
#pragma unroll
            for (int nf = 0; nf < 2; ++nf)
#pragma unroll
                for (int mi = 0; mi < 2; ++mi)
                    acc[mi][nf] = __builtin_amdgcn_mfma_f32_32x32x16_bf16(
                        af[mi * 4 + s], bf[nf * 4 + s], acc[mi][nf], 0, 0, 0);
        __builtin_amdgcn_s_setprio(0);

        // ---- tile end: drain t-1's loads (buf[(t+1)%3] ready); keep t's in flight ----
        if (pf) asm volatile("s_waitcnt vmcnt(6)" ::: "memory");
        else    asm volatile("s_waitcnt vmcnt(0)" ::: "memory");
        __builtin_amdgcn_s_barrier();

        rb = (rb + 1 == 3) ? 0 : rb + 1;
    }

    // ---- epilogue (C/D: col = l31, row = (reg&3) + 8*(reg>>2) + 4*lh) ----
    if constexpr (UP) {
        // n-frag 0 = gate chunk, n-frag 1 = up chunk (32-row cvtp interleave)
        const int hc0 = (n0 >> 1) + wc * 32 + l31;
        unsigned short* hb = (unsigned short*)outp;
#pragma unroll
        for (int mi = 0; mi < 2; ++mi) {
#pragma unroll
            for (int reg = 0; reg < 16; ++reg) {
                const int r = wr * 64 + mi * 32 + (reg & 3) + 8 * (reg >> 2) + 4 * lh;
                bool ok; size_t orow;
                if constexpr (MODE == 0) { ok = true; orow = (size_t)(r0 + r) * OSTR; }
                else { ok = (r0 + r < cnt); orow = (size_t)(gbase + r0 + r) * OSTR; }
                if (ok) {
                    float g = acc[mi][0][reg], u = acc[mi][1][reg];
                    hb[orow + hc0] = f2bf(g / (1.f + __expf(-g)) * u);
                }
            }
        }
    } else {
        float* op = (float*)outp;
        const int col0 = n0 + wc * 64 + l31;
#pragma unroll
        for (int mi = 0; mi < 2; ++mi) {
#pragma unroll
            for (int reg = 0; reg < 16; ++reg) {
                const int r = wr * 64 + mi * 32 + (reg & 3) + 8 * (reg >> 2) + 4 * lh;
                int tok; float scale; bool ok;
                if constexpr (MODE == 1) {
                    tok = r0 + r; scale = sg[tok]; ok = true;
                } else {
                    ok = (r0 + r < cnt);
                    int idx = ok ? (e * M_TOK + r0 + r) : (e * M_TOK);
                    tok = ltok[idx]; scale = lcoef[idx];
                }
                if (ok) {
                    size_t orow = (size_t)tok * H_DIM;
                    atomicAdd(op + orow + col0,      acc[mi][0][reg] * scale);
                    atomicAdd(op + orow + col0 + 32, acc[mi][1][reg] * scale);
                }
            }
        }
    }
}

extern "C" void kernel_launch(void* const* d_in, const int* in_sizes, int n_in,
                              void* d_out, int out_size, void* d_ws, size_t ws_size,
                              hipStream_t stream) {
    const float* x    = (const float*)d_in[0];
    const float* gw   = (const float*)d_in[1];
    const float* sgw  = (const float*)d_in[2];
    const float* w13  = (const float*)d_in[3];
    const float* w2   = (const float*)d_in[4];
    const float* sguw = (const float*)d_in[5];
    const float* sdw  = (const float*)d_in[6];
    float* out = (float*)d_out;

    char* ws = (char*)d_ws;
    unsigned short* xb    = (unsigned short*)ws;                // 16,777,216 B
    unsigned short* hbuf  = (unsigned short*)(ws + 16777216);   // 46,137,344 B (hs then he)
    unsigned short* w13b  = (unsigned short*)(ws + 62914560);   // 184,549,376 B (permuted)
    unsigned short* w2b   = (unsigned short*)(ws + 247463936);  //  92,274,688 B
    unsigned short* sguwb = (unsigned short*)(ws + 339738624);  //  46,137,344 B (permuted)
    unsigned short* sdwb  = (unsigned short*)(ws + 385875968);  //  23,068,672 B
    size_t so = 408944640ULL;
    int*   ltok   = (int*)  (ws + so);
    float* lcoef  = (float*)(ws + so + 262144);
    int*   counts = (int*)  (ws + so + 524288);
    int*   basep  = (int*)  (ws + so + 524288 + 256);
    float* sg     = (float*)(ws + so + 524288 + 512);

    hipMemsetAsync(counts, 0, 64, stream);
    hipMemsetAsync(out, 0, (size_t)out_size * sizeof(float), stream);
    k_router<<<M_TOK / 4, 256, 0, stream>>>(x, gw, sgw, counts, ltok, lcoef, sg);
    k_prefix<<<1, 64, 0, stream>>>(counts, basep);
    k_cvtw<<<4096, 256, 0, stream>>>(x, xb, (size_t)M_TOK * H_DIM / 8);
    k_cvtp<2 * IS_DIM, IS_DIM><<<8192, 256, 0, stream>>>(sguw, sguwb, (size_t)2 * IS_DIM * H_DIM / 8);
    k_cvtw<<<8192, 256, 0, stream>>>(sdw,  sdwb,  (size_t)H_DIM * IS_DIM / 8);
    k_cvtp<2 * I_DIM, I_DIM><<<8192, 256, 0, stream>>>(w13, w13b, (size_t)E_NUM * 2 * I_DIM * H_DIM / 8);
    k_cvtw<<<8192, 256, 0, stream>>>(w2,   w2b,   (size_t)E_NUM * H_DIM * I_DIM / 8);

    static const int DYN = 147456;   // 3 x (32 KiB A + 16 KiB B)
    (void)hipFuncSetAttribute(reinterpret_cast<const void*>(&k_gemm<0, 2048, 0LL, 1>),
                              hipFuncAttributeMaxDynamicSharedMemorySize, DYN);
    (void)hipFuncSetAttribute(reinterpret_cast<const void*>(&k_gemm<1, 5632, 0LL, 2>),
                              hipFuncAttributeMaxDynamicSharedMemorySize, DYN);
    (void)hipFuncSetAttribute(reinterpret_cast<const void*>(&k_gemm<2, 2048, 5767168LL, 1>),
                              hipFuncAttributeMaxDynamicSharedMemorySize, DYN);
    (void)hipFuncSetAttribute(reinterpret_cast<const void*>(&k_gemm<3, 1408, 2883584LL, 1>),
                              hipFuncAttributeMaxDynamicSharedMemorySize, DYN);

    // shared up: xb[4096,2048] x sguwb^T -> silu-mul pairs -> hs bf16 [4096,5632]
    k_gemm<0, 2048, 0LL, 1>
        <<<dim3(2 * IS_DIM / 128, M_TOK / 256, 1), 512, DYN, stream>>>(
            xb, sguwb, hbuf, ltok, lcoef, counts, basep, sg);
    // shared down (split-K=2): hs x sdwb^T * sg -> atomicAdd out
    k_gemm<1, 5632, 0LL, 2>
        <<<dim3(H_DIM / 128, M_TOK / 256, 2), 512, DYN, stream>>>(
            hbuf, sdwb, out, ltok, lcoef, counts, basep, sg);
    // expert up (gathered): xb x w13b_e^T -> silu-mul -> he bf16 [16384,1408]
    k_gemm<2, 2048, 5767168LL, 1>
        <<<dim3(2 * I_DIM / 128, M_TOK / 256, E_NUM), 512, DYN, stream>>>(
            xb, w13b, hbuf, ltok, lcoef, counts, basep, sg);
    // expert down: he x w2b_e^T * coef -> atomicAdd out
    k_gemm<3, 1408, 2883584LL, 1>
        <<<dim3(H_DIM / 128, M_TOK / 256, E_NUM), 512, DYN, stream>>>(
            hbuf, w2b, out, ltok, lcoef, counts, basep, sg);
}